// Round 7
// baseline (1018.240 us; speedup 1.0000x reference)
//
#include <hip/hip_runtime.h>
#include <math.h>

#define PI_D 3.14159265358979323846

// ---------------- dims ----------------
#define BATCH   1024
#define TLEN    16000
#define NFFT    400
#define HOP     200
#define NFRAME  81          // 1 + (16400-400)/200
#define NBIN    201
#define NMEL    128
#define HID     128
#define TSTEPS  79          // after conv k=3 valid
#define GATES   512         // 4*HID

#define KDFT    416         // 400 padded to 32
#define NDFT    448         // cos 0..200, sin 224..424, rest zero
#define KPOW    224         // 201 padded to 32
#define KCONV   384
#define NCHUNK  8
#define CHROWS  (BATCH*NFRAME/NCHUNK)   // 10368

static inline size_t al512(size_t v){ return (v + 511) & ~((size_t)511); }

// ---------------- bf16 split helpers ----------------
__device__ __forceinline__ unsigned short bf_rne(float f){
    unsigned u = __float_as_uint(f);
    u += 0x7FFF + ((u >> 16) & 1);
    return (unsigned short)(u >> 16);
}
__device__ __forceinline__ void bf_split(float f, unsigned short& h, unsigned short& l){
    h = bf_rne(f);
    float hf = __uint_as_float(((unsigned)h) << 16);
    l = bf_rne(f - hf);
}
// Fast truncation split (GEMM staging hot path)
__device__ __forceinline__ void bf_split_fast(float f, unsigned short& h, unsigned short& l){
    unsigned u = __float_as_uint(f);
    h = (unsigned short)(u >> 16);
    float hf = __uint_as_float(u & 0xFFFF0000u);
    l = (unsigned short)(__float_as_uint(f - hf) >> 16);
}

typedef short bf16x8 __attribute__((ext_vector_type(8)));
typedef float f32x4  __attribute__((ext_vector_type(4)));
typedef unsigned short us8 __attribute__((ext_vector_type(8)));
typedef _Float16 f16x8 __attribute__((ext_vector_type(8)));

// ---------------- setup kernels ----------------
__global__ void setup_dft_t(unsigned short* __restrict__ th, unsigned short* __restrict__ tl){
    int idx = blockIdx.x*256 + threadIdx.x;
    if (idx >= NDFT*KDFT) return;
    int n = idx / KDFT, k = idx % KDFT;
    double v = 0.0;
    if (k < 400) {
        double w = 0.5 - 0.5*cos(2.0*PI_D*(double)k/400.0);
        if (n < NBIN)                v = w * cos(2.0*PI_D*(double)((k*n)%400)/400.0);
        else if (n >= 224 && n < 425) v = w * sin(2.0*PI_D*(double)((k*(n-224))%400)/400.0);
    }
    unsigned short h, l; bf_split((float)v, h, l);
    th[idx] = h; tl[idx] = l;
}

__global__ void setup_fb_t(unsigned short* __restrict__ fh, unsigned short* __restrict__ fl){
    int idx = blockIdx.x*256 + threadIdx.x;
    if (idx >= NMEL*KPOW) return;
    int m = idx / KPOW, f = idx % KPOW;
    float v = 0.f;
    if (f < NBIN) {
        double melmax = 2595.0 * log10(1.0 + 8000.0/700.0);
        double p0 = 700.0*(pow(10.0, melmax*(double)(m  )/129.0/2595.0) - 1.0);
        double p1 = 700.0*(pow(10.0, melmax*(double)(m+1)/129.0/2595.0) - 1.0);
        double p2 = 700.0*(pow(10.0, melmax*(double)(m+2)/129.0/2595.0) - 1.0);
        double freq = 40.0 * (double)f;
        double dn = (freq - p0)/(p1 - p0);
        double up = (p2 - freq)/(p2 - p1);
        double t  = dn < up ? dn : up;
        if (t < 0.0) t = 0.0;
        v = (float)t;
    }
    unsigned short h, l; bf_split(v, h, l);
    fh[idx] = h; fl[idx] = l;
}

__global__ void setup_wc_t(unsigned short* __restrict__ wh, unsigned short* __restrict__ wl,
                           const float* __restrict__ cw){
    int idx = blockIdx.x*256 + threadIdx.x;
    if (idx >= NMEL*KCONV) return;
    int o = idx / KCONV, kk = idx % KCONV;
    int ksh = kk >> 7, i = kk & 127;
    unsigned short h, l; bf_split(cw[o*384 + i*3 + ksh], h, l);
    wh[idx] = h; wl[idx] = l;
}

__global__ void setup_w_t(unsigned short* __restrict__ wh, unsigned short* __restrict__ wl,
                          const float* __restrict__ w){
    int idx = blockIdx.x*256 + threadIdx.x;
    if (idx >= GATES*HID) return;
    int c = idx / HID, i = idx % HID;
    unsigned short h, l; bf_split(w[(size_t)i*GATES + c], h, l);
    wh[idx] = h; wl[idx] = l;
}

__global__ void setup_comb(float* __restrict__ cwm, float* __restrict__ cb,
                           const float* __restrict__ fc1w, const float* __restrict__ fc1b,
                           const float* __restrict__ projw, const float* __restrict__ projb){
    int idx = blockIdx.x*256 + threadIdx.x;
    if (idx < 128*64) {
        int i = idx / 64, o = idx % 64;
        float v = 0.f;
        if (o < 35) {
            double s = 0.0;
            for (int m = 0; m < 128; m++) s += (double)fc1w[i*128+m] * (double)projw[m*35+o];
            v = (float)s;
        }
        cwm[idx] = v;
    } else if (idx < 128*64 + 64) {
        int o = idx - 128*64;
        float v = 0.f;
        if (o < 35) {
            double s = (double)projb[o];
            for (int m = 0; m < 128; m++) s += (double)fc1b[m] * (double)projw[m*35+o];
            v = (float)s;
        }
        cb[o] = v;
    }
}

// U (HID x GATES row-major) -> fp16 in MFMA B-fragment order.
__global__ void setup_uf(_Float16* __restrict__ uf, const float* __restrict__ u){
    int idx = blockIdx.x*256 + threadIdx.x;
    if (idx >= 65536) return;
    int j    = idx & 7;
    int lane = (idx >> 3) & 63;
    int nt   = (idx >> 9) & 3;
    int ks   = (idx >> 11) & 3;
    int w    = (idx >> 13) & 7;
    int k = ks*32 + (lane >> 4)*8 + j;
    int c = w*64 + nt*16 + (lane & 15);
    uf[idx] = (_Float16)u[(size_t)k*GATES + c];
}

// ---------------- MFMA split-bf16 GEMM, 128x64 tile ----------------
enum AMode { A_NORMAL=0, A_FRAMES=1, A_POWER=2, A_CONV3=3 };
#define LDK 40

template<int AMODE>
__device__ __forceinline__ void load_a8(const float* __restrict__ A,
                                        const float* __restrict__ aux, int rowbase,
                                        int row, int kk, int lda, float* v)
{
    if constexpr (AMODE == A_NORMAL) {
        *(float4*)&v[0] = *(const float4*)(A + (size_t)row*lda + kk);
        *(float4*)&v[4] = *(const float4*)(A + (size_t)row*lda + kk + 4);
    } else if constexpr (AMODE == A_POWER) {
        float4 re0 = *(const float4*)(A + (size_t)row*lda + kk);
        float4 re1 = *(const float4*)(A + (size_t)row*lda + kk + 4);
        float4 im0 = *(const float4*)(A + (size_t)row*lda + 224 + kk);
        float4 im1 = *(const float4*)(A + (size_t)row*lda + 224 + kk + 4);
        v[0]=re0.x*re0.x+im0.x*im0.x; v[1]=re0.y*re0.y+im0.y*im0.y;
        v[2]=re0.z*re0.z+im0.z*im0.z; v[3]=re0.w*re0.w+im0.w*im0.w;
        v[4]=re1.x*re1.x+im1.x*im1.x; v[5]=re1.y*re1.y+im1.y*im1.y;
        v[6]=re1.z*re1.z+im1.z*im1.z; v[7]=re1.w*re1.w+im1.w*im1.w;
    } else if constexpr (AMODE == A_FRAMES) {
        const int r = rowbase + row;
        const int b = r / NFRAME, f = r - b*NFRAME;
        const float* xb = aux + (size_t)b * TLEN;
        #pragma unroll
        for (int j = 0; j < 8; j++) {
            int q = f*HOP + (kk + j) - 200;
            if (q < 0) q = -q;
            else if (q >= TLEN) q = 2*TLEN - 2 - q;
            v[j] = xb[q];
        }
    } else { // A_CONV3
        const int b = row / TSTEPS, t = row - b*TSTEPS;
        const int ksh = kk >> 7, i = kk & 127;
        const float* src = aux + ((size_t)(b*NFRAME + t + ksh)*NMEL + i);
        *(float4*)&v[0] = *(const float4*)(src);
        *(float4*)&v[4] = *(const float4*)(src + 4);
    }
}

template<int AMODE, bool BIAS>
__global__ __launch_bounds__(256)
void mgemm_k(const float* __restrict__ A,
             const unsigned short* __restrict__ BTh, const unsigned short* __restrict__ BTl,
             const float* __restrict__ bias, float* __restrict__ C,
             int M, int Ksteps, int lda, int kstride, int ldc,
             const float* __restrict__ aux, int rowbase)
{
    __shared__ unsigned short Ash[128][LDK], Asl[128][LDK];
    __shared__ unsigned short Bsh[64][LDK], Bsl[64][LDK];

    const int tid = threadIdx.x;
    const int m0 = blockIdx.x * 128;
    const int n0 = blockIdx.y * 64;
    const int am = tid >> 2, k8 = (tid & 3) * 8;

    const int lane = tid & 63, w = tid >> 6;     // 4 waves
    const int m16 = lane & 15, quad = lane >> 4;
    const int koff = quad * 8;

    f32x4 acc[2][4] = {{{0,0,0,0},{0,0,0,0},{0,0,0,0},{0,0,0,0}},
                       {{0,0,0,0},{0,0,0,0},{0,0,0,0},{0,0,0,0}}};

    for (int ks = 0; ks < Ksteps; ks++) {
        const int k0 = ks * 32;
        // ---- stage A: two rows per thread (am, am+64) ----
        {
            const int kk = k0 + k8;
            float v[8];
            us8 hv, lv;
            load_a8<AMODE>(A, aux, rowbase, m0 + am, kk, lda, v);
            #pragma unroll
            for (int j = 0; j < 8; j++) { unsigned short h,l; bf_split_fast(v[j],h,l); hv[j]=h; lv[j]=l; }
            *(us8*)&Ash[am][k8] = hv;  *(us8*)&Asl[am][k8] = lv;
            load_a8<AMODE>(A, aux, rowbase, m0 + am + 64, kk, lda, v);
            #pragma unroll
            for (int j = 0; j < 8; j++) { unsigned short h,l; bf_split_fast(v[j],h,l); hv[j]=h; lv[j]=l; }
            *(us8*)&Ash[am+64][k8] = hv;  *(us8*)&Asl[am+64][k8] = lv;
        }
        // ---- stage B (pre-split, pure copy) ----
        {
            const size_t o = (size_t)(n0 + am)*kstride + k0 + k8;
            *(us8*)&Bsh[am][k8] = *(const us8*)(BTh + o);
            *(us8*)&Bsl[am][k8] = *(const us8*)(BTl + o);
        }
        __syncthreads();

        // wave w owns M-subtiles 2w, 2w+1; B-frag read shared by both
        bf16x8 ah[2], al[2];
        #pragma unroll
        for (int p = 0; p < 2; p++) {
            const int mr = (w*2 + p)*16 + m16;
            ah[p] = *(const bf16x8*)&Ash[mr][koff];
            al[p] = *(const bf16x8*)&Asl[mr][koff];
        }
        #pragma unroll
        for (int nt = 0; nt < 4; nt++) {
            const int nr = nt*16 + m16;
            bf16x8 bh = *(const bf16x8*)&Bsh[nr][koff];
            bf16x8 bl = *(const bf16x8*)&Bsl[nr][koff];
            #pragma unroll
            for (int p = 0; p < 2; p++) {
                acc[p][nt] = __builtin_amdgcn_mfma_f32_16x16x32_bf16(ah[p], bh, acc[p][nt], 0, 0, 0);
                acc[p][nt] = __builtin_amdgcn_mfma_f32_16x16x32_bf16(ah[p], bl, acc[p][nt], 0, 0, 0);
                acc[p][nt] = __builtin_amdgcn_mfma_f32_16x16x32_bf16(al[p], bh, acc[p][nt], 0, 0, 0);
            }
        }
        __syncthreads();
    }

    // ---- epilogue: C/D layout col=lane&15, row=quad*4+reg ----
    #pragma unroll
    for (int p = 0; p < 2; p++) {
        #pragma unroll
        for (int nt = 0; nt < 4; nt++) {
            const int col = n0 + nt*16 + m16;
            float b = 0.f;
            if constexpr (BIAS) b = bias[col];
            #pragma unroll
            for (int r = 0; r < 4; r++) {
                const int row = m0 + (w*2 + p)*16 + quad*4 + r;
                C[(size_t)row*ldc + col] = acc[p][nt][r] + b;
            }
        }
    }
    (void)M;
}

// ---------------- small fp32 GEMM (final 1024x35 only) ----------------
__global__ __launch_bounds__(256)
void gemm_small(const float* __restrict__ A, const float* __restrict__ Bm,
                const float* __restrict__ bias, float* __restrict__ C,
                int M, int N, int K, int lda, int ldb, int ldc)
{
    __shared__ float As[16][64+4];
    __shared__ float Bs[16][64];
    const int tid = threadIdx.x;
    const int tx = tid & 15, ty = tid >> 4;
    const int m0 = blockIdx.x * 64;
    float acc[4][4] = {{0,0,0,0},{0,0,0,0},{0,0,0,0},{0,0,0,0}};
    const int am = tid >> 2, ak = (tid & 3) * 4;
    const int bk = tid >> 4, bn = (tid & 15) * 4;
    for (int k0 = 0; k0 < K; k0 += 16) {
        float4 av = *(const float4*)(A + (size_t)(m0+am)*lda + k0 + ak);
        As[ak+0][am]=av.x; As[ak+1][am]=av.y; As[ak+2][am]=av.z; As[ak+3][am]=av.w;
        *(float4*)&Bs[bk][bn] = *(const float4*)(Bm + (size_t)(k0+bk)*ldb + bn);
        __syncthreads();
        #pragma unroll
        for (int k = 0; k < 16; k++) {
            float4 a = *(const float4*)&As[k][ty*4];
            float4 b = *(const float4*)&Bs[k][tx*4];
            #pragma unroll
            for (int i = 0; i < 4; i++) {
                float av_ = ((const float*)&a)[i];
                acc[i][0] = fmaf(av_, b.x, acc[i][0]);
                acc[i][1] = fmaf(av_, b.y, acc[i][1]);
                acc[i][2] = fmaf(av_, b.z, acc[i][2]);
                acc[i][3] = fmaf(av_, b.w, acc[i][3]);
            }
        }
        __syncthreads();
    }
    #pragma unroll
    for (int ir = 0; ir < 4; ir++) {
        const int row = m0 + ty*4 + ir;
        #pragma unroll
        for (int jc = 0; jc < 4; jc++) {
            const int col = tx*4 + jc;
            if (col < N) C[(size_t)row*ldc + col] = acc[ir][jc] + bias[col];
        }
    }
}

// ---------------- LSTM recurrence: MFMA, U pinned in AGPRs ----------------
__device__ __forceinline__ float sigm_f(float x){ return 1.f/(1.f + __expf(-x)); }
__device__ __forceinline__ float tanh_f(float x){ float e = __expf(2.f*x); return 1.f - 2.f/(e + 1.f); }

#define LROWS 4
#define LTHREADS 512
#define HPAD 136

// launch_bounds(512,1): only 1 WG/CU runs anyway (grid=256); the 512-reg
// budget removes the allocator's spill motive (R5: remat @ 84 VGPR; R6:
// scratch-spill @ 56 VGPR under the 2-waves/EU budget — both L2-bound).
__global__ __launch_bounds__(LTHREADS, 1)
void lstm_k(const float* __restrict__ X, const _Float16* __restrict__ Uf, float* __restrict__ H)
{
    __shared__ _Float16 hsA[16*HPAD];
    __shared__ float gs[GATES*5];
    const int tid = threadIdx.x;
    const int b0 = blockIdx.x * LROWS;
    const int lane = tid & 63, w = tid >> 6;
    const int m16 = lane & 15, quad = lane >> 4;
    const int r = tid >> 7;
    const int j = tid & 127;

    // Preload U fragments and pin them in the ACCUMULATOR file: "a" class
    // keeps VGPR pressure low (~60) while 64 AGPRs hold U. Volatile asm def
    // is non-rematerializable; gfx950 MFMA can consume AGPR B-operands.
    f32x4 bfr[4][4];
    #pragma unroll
    for (int ks = 0; ks < 4; ks++)
        #pragma unroll
        for (int nt = 0; nt < 4; nt++)
            bfr[ks][nt] = *(const f32x4*)(Uf + ((((w*4 + ks)*4 + nt)*64 + lane) << 3));
    #pragma unroll
    for (int ks = 0; ks < 4; ks++)
        #pragma unroll
        for (int nt = 0; nt < 4; nt++)
            asm volatile("" : "+a"(bfr[ks][nt]));

    for (int i = tid; i < 16*HPAD; i += LTHREADS) hsA[i] = (_Float16)0.f;
    float cst = 0.f;
    const float* xb = X + ((size_t)(b0 + r)*TSTEPS)*GATES + j;
    __syncthreads();

    float xi = xb[0], xf = xb[128], xg = xb[256], xo = xb[384];

    for (int t = 0; t < TSTEPS; t++) {
        float xi_n = 0.f, xf_n = 0.f, xg_n = 0.f, xo_n = 0.f;
        if (t + 1 < TSTEPS) {
            const float* xp = xb + (size_t)(t + 1)*GATES;
            xi_n = xp[0]; xf_n = xp[128]; xg_n = xp[256]; xo_n = xp[384];
        }

        f16x8 ah[4];
        #pragma unroll
        for (int ks = 0; ks < 4; ks++)
            ah[ks] = *(const f16x8*)&hsA[m16*HPAD + ks*32 + quad*8];

        f32x4 acc[4] = {{0,0,0,0},{0,0,0,0},{0,0,0,0},{0,0,0,0}};
        #pragma unroll
        for (int ks = 0; ks < 4; ks++)
            #pragma unroll
            for (int nt = 0; nt < 4; nt++)
                acc[nt] = __builtin_amdgcn_mfma_f32_16x16x32_f16(
                    ah[ks], __builtin_bit_cast(f16x8, bfr[ks][nt]), acc[nt], 0, 0, 0);

        if (quad == 0) {
            #pragma unroll
            for (int nt = 0; nt < 4; nt++) {
                const int c = w*64 + nt*16 + m16;
                #pragma unroll
                for (int rr = 0; rr < 4; rr++) gs[c*5 + rr] = acc[nt][rr];
            }
        }
        __syncthreads();

        {
            const float gi = gs[(      j)*5 + r] + xi;
            const float gf = gs[(128 + j)*5 + r] + xf;
            const float gg = gs[(256 + j)*5 + r] + xg;
            const float go = gs[(384 + j)*5 + r] + xo;
            const float cn = sigm_f(gf)*cst + sigm_f(gi)*tanh_f(gg);
            cst = cn;
            const float hn = sigm_f(go)*tanh_f(cn);
            H[((size_t)(b0 + r)*TSTEPS + t)*HID + j] = hn;
            hsA[r*HPAD + j] = (_Float16)hn;
        }
        __syncthreads();

        xi = xi_n; xf = xf_n; xg = xg_n; xo = xo_n;
    }
}

// ---------------- mean over time ----------------
__global__ void mean_k(const float* __restrict__ H, float* __restrict__ Mh){
    const int idx = blockIdx.x*256 + threadIdx.x;
    if (idx >= BATCH*HID) return;
    const int b = idx >> 7, j = idx & 127;
    const float* p = H + (size_t)b*TSTEPS*HID + j;
    float s = 0.f;
    for (int t = 0; t < TSTEPS; t++) s += p[(size_t)t*HID];
    Mh[idx] = s * (1.0f/(float)TSTEPS);
}

// ---------------- launcher ----------------
extern "C" void kernel_launch(void* const* d_in, const int* in_sizes, int n_in,
                              void* d_out, int out_size, void* d_ws, size_t ws_size,
                              hipStream_t stream)
{
    const float* x      = (const float*)d_in[0];
    const float* conv_w = (const float*)d_in[1];
    const float* conv_b = (const float*)d_in[2];
    const float* W1     = (const float*)d_in[3];
    const float* U1     = (const float*)d_in[4];
    const float* b1     = (const float*)d_in[5];
    const float* W2     = (const float*)d_in[6];
    const float* U2     = (const float*)d_in[7];
    const float* b2     = (const float*)d_in[8];
    const float* fc1_w  = (const float*)d_in[9];
    const float* fc1_b  = (const float*)d_in[10];
    const float* proj_w = (const float*)d_in[11];
    const float* proj_b = (const float*)d_in[12];
    float* out = (float*)d_out;

    // ---- workspace layout (~240 MiB < 256 MiB) ----
    char* ws = (char*)d_ws;
    size_t off = 0;
    unsigned short* Tth = (unsigned short*)(ws + off); off = al512(off + (size_t)NDFT*KDFT*2);
    unsigned short* Ttl = (unsigned short*)(ws + off); off = al512(off + (size_t)NDFT*KDFT*2);
    unsigned short* fbh = (unsigned short*)(ws + off); off = al512(off + (size_t)NMEL*KPOW*2);
    unsigned short* fbl = (unsigned short*)(ws + off); off = al512(off + (size_t)NMEL*KPOW*2);
    unsigned short* wch = (unsigned short*)(ws + off); off = al512(off + (size_t)NMEL*KCONV*2);
    unsigned short* wcl = (unsigned short*)(ws + off); off = al512(off + (size_t)NMEL*KCONV*2);
    unsigned short* w1h = (unsigned short*)(ws + off); off = al512(off + (size_t)GATES*HID*2);
    unsigned short* w1l = (unsigned short*)(ws + off); off = al512(off + (size_t)GATES*HID*2);
    unsigned short* w2h = (unsigned short*)(ws + off); off = al512(off + (size_t)GATES*HID*2);
    unsigned short* w2l = (unsigned short*)(ws + off); off = al512(off + (size_t)GATES*HID*2);
    float* Cw   = (float*)(ws + off); off = al512(off + (size_t)128*64*4);
    float* Cb   = (float*)(ws + off); off = al512(off + (size_t)64*4);
    float* Mh   = (float*)(ws + off); off = al512(off + (size_t)BATCH*HID*4);
    _Float16* Uf1 = (_Float16*)(ws + off); off = al512(off + (size_t)65536*2);
    _Float16* Uf2 = (_Float16*)(ws + off); off = al512(off + (size_t)65536*2);
    float* MEL  = (float*)(ws + off); off = al512(off + (size_t)BATCH*NFRAME*NMEL*4);   // 42.5 MB
    float* CONV = (float*)(ws + off); off = al512(off + (size_t)BATCH*TSTEPS*NMEL*4);   // 41.4 MB
    float* X    = (float*)(ws + off); off = al512(off + (size_t)BATCH*TSTEPS*GATES*4);  // 165.7 MB
    float* DFT = X;     // DFT chunk scratch dead before X written
    float* H1  = MEL;   // MEL dead after CONV computed
    float* H2  = CONV;  // CONV dead after X1 computed
    (void)ws_size; (void)out_size; (void)n_in; (void)in_sizes;

    // setup tables
    setup_dft_t<<<(NDFT*KDFT + 255)/256, 256, 0, stream>>>(Tth, Ttl);
    setup_fb_t <<<(NMEL*KPOW + 255)/256, 256, 0, stream>>>(fbh, fbl);
    setup_wc_t <<<(NMEL*KCONV + 255)/256, 256, 0, stream>>>(wch, wcl, conv_w);
    setup_w_t  <<<(GATES*HID + 255)/256, 256, 0, stream>>>(w1h, w1l, W1);
    setup_w_t  <<<(GATES*HID + 255)/256, 256, 0, stream>>>(w2h, w2l, W2);
    setup_comb <<<(128*64 + 64 + 255)/256, 256, 0, stream>>>(Cw, Cb, fc1_w, fc1_b, proj_w, proj_b);
    setup_uf   <<<65536/256, 256, 0, stream>>>(Uf1, U1);
    setup_uf   <<<65536/256, 256, 0, stream>>>(Uf2, U2);

    // mel spectrogram in chunks: frames @ DFT -> power @ fb
    for (int ch = 0; ch < NCHUNK; ch++) {
        const int rowbase = ch * CHROWS;
        mgemm_k<A_FRAMES,false><<<dim3(CHROWS/128, NDFT/64), 256, 0, stream>>>(
            nullptr, Tth, Ttl, nullptr, DFT, CHROWS, KDFT/32, 0, KDFT, NDFT, x, rowbase);
        mgemm_k<A_POWER,false><<<dim3(CHROWS/128, NMEL/64), 256, 0, stream>>>(
            DFT, fbh, fbl, nullptr, MEL + (size_t)rowbase*NMEL, CHROWS, KPOW/32, NDFT, KPOW, NMEL, nullptr, 0);
    }

    // conv1d (k=3, valid) as im2col GEMM, bias fused
    mgemm_k<A_CONV3,true><<<dim3(BATCH*TSTEPS/128, NMEL/64), 256, 0, stream>>>(
        nullptr, wch, wcl, conv_b, CONV, BATCH*TSTEPS, KCONV/32, 0, KCONV, NMEL, MEL, 0);

    // layer 1: X1 = CONV @ W1 + b1 ; recurrence
    mgemm_k<A_NORMAL,true><<<dim3(BATCH*TSTEPS/128, GATES/64), 256, 0, stream>>>(
        CONV, w1h, w1l, b1, X, BATCH*TSTEPS, HID/32, NMEL, HID, GATES, nullptr, 0);
    lstm_k<<<BATCH/LROWS, LTHREADS, 0, stream>>>(X, Uf1, H1);

    // layer 2
    mgemm_k<A_NORMAL,true><<<dim3(BATCH*TSTEPS/128, GATES/64), 256, 0, stream>>>(
        H1, w2h, w2l, b2, X, BATCH*TSTEPS, HID/32, HID, HID, GATES, nullptr, 0);
    lstm_k<<<BATCH/LROWS, LTHREADS, 0, stream>>>(X, Uf2, H2);

    // mean over time, then folded fc1+proj
    mean_k<<<(BATCH*HID + 255)/256, 256, 0, stream>>>(H2, Mh);
    gemm_small<<<BATCH/64, 256, 0, stream>>>(Mh, Cw, Cb, out, BATCH, 35, HID, HID, 64, 35);
}

// Round 8
// 1013.964 us; speedup vs baseline: 1.0042x; 1.0042x over previous
//
#include <hip/hip_runtime.h>
#include <math.h>

#define PI_D 3.14159265358979323846

// ---------------- dims ----------------
#define BATCH   1024
#define TLEN    16000
#define NFFT    400
#define HOP     200
#define NFRAME  81          // 1 + (16400-400)/200
#define NBIN    201
#define NMEL    128
#define HID     128
#define TSTEPS  79          // after conv k=3 valid
#define GATES   512         // 4*HID

#define KDFT    416         // 400 padded to 32
#define NDFT    448         // cos 0..200, sin 224..424, rest zero
#define KPOW    224         // 201 padded to 32
#define KCONV   384
#define MROWS   (BATCH*NFRAME)   // 82944

static inline size_t al512(size_t v){ return (v + 511) & ~((size_t)511); }

// ---------------- bf16 split helpers ----------------
__device__ __forceinline__ unsigned short bf_rne(float f){
    unsigned u = __float_as_uint(f);
    u += 0x7FFF + ((u >> 16) & 1);
    return (unsigned short)(u >> 16);
}
__device__ __forceinline__ void bf_split(float f, unsigned short& h, unsigned short& l){
    h = bf_rne(f);
    float hf = __uint_as_float(((unsigned)h) << 16);
    l = bf_rne(f - hf);
}
__device__ __forceinline__ void bf_split_fast(float f, unsigned short& h, unsigned short& l){
    unsigned u = __float_as_uint(f);
    h = (unsigned short)(u >> 16);
    float hf = __uint_as_float(u & 0xFFFF0000u);
    l = (unsigned short)(__float_as_uint(f - hf) >> 16);
}

typedef short bf16x8 __attribute__((ext_vector_type(8)));
typedef float f32x4  __attribute__((ext_vector_type(4)));
typedef unsigned short us8 __attribute__((ext_vector_type(8)));
typedef _Float16 f16x8 __attribute__((ext_vector_type(8)));

// ---------------- setup kernels ----------------
__global__ void setup_dft_t(unsigned short* __restrict__ th, unsigned short* __restrict__ tl){
    int idx = blockIdx.x*256 + threadIdx.x;
    if (idx >= NDFT*KDFT) return;
    int n = idx / KDFT, k = idx % KDFT;
    double v = 0.0;
    if (k < 400) {
        double w = 0.5 - 0.5*cos(2.0*PI_D*(double)k/400.0);
        if (n < NBIN)                v = w * cos(2.0*PI_D*(double)((k*n)%400)/400.0);
        else if (n >= 224 && n < 425) v = w * sin(2.0*PI_D*(double)((k*(n-224))%400)/400.0);
    }
    unsigned short h, l; bf_split((float)v, h, l);
    th[idx] = h; tl[idx] = l;
}

__global__ void setup_fb_t(unsigned short* __restrict__ fh, unsigned short* __restrict__ fl){
    int idx = blockIdx.x*256 + threadIdx.x;
    if (idx >= NMEL*KPOW) return;
    int m = idx / KPOW, f = idx % KPOW;
    float v = 0.f;
    if (f < NBIN) {
        double melmax = 2595.0 * log10(1.0 + 8000.0/700.0);
        double p0 = 700.0*(pow(10.0, melmax*(double)(m  )/129.0/2595.0) - 1.0);
        double p1 = 700.0*(pow(10.0, melmax*(double)(m+1)/129.0/2595.0) - 1.0);
        double p2 = 700.0*(pow(10.0, melmax*(double)(m+2)/129.0/2595.0) - 1.0);
        double freq = 40.0 * (double)f;
        double dn = (freq - p0)/(p1 - p0);
        double up = (p2 - freq)/(p2 - p1);
        double t  = dn < up ? dn : up;
        if (t < 0.0) t = 0.0;
        v = (float)t;
    }
    unsigned short h, l; bf_split(v, h, l);
    fh[idx] = h; fl[idx] = l;
}

__global__ void setup_wc_t(unsigned short* __restrict__ wh, unsigned short* __restrict__ wl,
                           const float* __restrict__ cw){
    int idx = blockIdx.x*256 + threadIdx.x;
    if (idx >= NMEL*KCONV) return;
    int o = idx / KCONV, kk = idx % KCONV;
    int ksh = kk >> 7, i = kk & 127;
    unsigned short h, l; bf_split(cw[o*384 + i*3 + ksh], h, l);
    wh[idx] = h; wl[idx] = l;
}

__global__ void setup_w_t(unsigned short* __restrict__ wh, unsigned short* __restrict__ wl,
                          const float* __restrict__ w){
    int idx = blockIdx.x*256 + threadIdx.x;
    if (idx >= GATES*HID) return;
    int c = idx / HID, i = idx % HID;
    unsigned short h, l; bf_split(w[(size_t)i*GATES + c], h, l);
    wh[idx] = h; wl[idx] = l;
}

__global__ void setup_comb(float* __restrict__ cwm, float* __restrict__ cb,
                           const float* __restrict__ fc1w, const float* __restrict__ fc1b,
                           const float* __restrict__ projw, const float* __restrict__ projb){
    int idx = blockIdx.x*256 + threadIdx.x;
    if (idx < 128*64) {
        int i = idx / 64, o = idx % 64;
        float v = 0.f;
        if (o < 35) {
            double s = 0.0;
            for (int m = 0; m < 128; m++) s += (double)fc1w[i*128+m] * (double)projw[m*35+o];
            v = (float)s;
        }
        cwm[idx] = v;
    } else if (idx < 128*64 + 64) {
        int o = idx - 128*64;
        float v = 0.f;
        if (o < 35) {
            double s = (double)projb[o];
            for (int m = 0; m < 128; m++) s += (double)fc1b[m] * (double)projw[m*35+o];
            v = (float)s;
        }
        cb[o] = v;
    }
}

// U (HID x GATES row-major) -> fp16 in MFMA B-fragment order.
__global__ void setup_uf(_Float16* __restrict__ uf, const float* __restrict__ u){
    int idx = blockIdx.x*256 + threadIdx.x;
    if (idx >= 65536) return;
    int j    = idx & 7;
    int lane = (idx >> 3) & 63;
    int nt   = (idx >> 9) & 3;
    int ks   = (idx >> 11) & 3;
    int w    = (idx >> 13) & 7;
    int k = ks*32 + (lane >> 4)*8 + j;
    int c = w*64 + nt*16 + (lane & 15);
    uf[idx] = (_Float16)u[(size_t)k*GATES + c];
}

// ---------------- MFMA split-bf16 GEMM: 64x64 tile, LDS double-buffered ----------------
enum AMode { A_NORMAL=0, A_FRAMES=1, A_POWER=2, A_CONV3=3 };
#define LDK 40

template<int AMODE>
__device__ __forceinline__ void load_a8(const float* __restrict__ A,
                                        const float* __restrict__ aux, int rowbase,
                                        int row, int kk, int lda, float* v)
{
    if constexpr (AMODE == A_NORMAL) {
        *(float4*)&v[0] = *(const float4*)(A + (size_t)row*lda + kk);
        *(float4*)&v[4] = *(const float4*)(A + (size_t)row*lda + kk + 4);
    } else if constexpr (AMODE == A_POWER) {
        float4 re0 = *(const float4*)(A + (size_t)row*lda + kk);
        float4 re1 = *(const float4*)(A + (size_t)row*lda + kk + 4);
        float4 im0 = *(const float4*)(A + (size_t)row*lda + 224 + kk);
        float4 im1 = *(const float4*)(A + (size_t)row*lda + 224 + kk + 4);
        v[0]=re0.x*re0.x+im0.x*im0.x; v[1]=re0.y*re0.y+im0.y*im0.y;
        v[2]=re0.z*re0.z+im0.z*im0.z; v[3]=re0.w*re0.w+im0.w*im0.w;
        v[4]=re1.x*re1.x+im1.x*im1.x; v[5]=re1.y*re1.y+im1.y*im1.y;
        v[6]=re1.z*re1.z+im1.z*im1.z; v[7]=re1.w*re1.w+im1.w*im1.w;
    } else if constexpr (AMODE == A_FRAMES) {
        const int r = rowbase + row;
        const int b = r / NFRAME, f = r - b*NFRAME;
        const float* xb = aux + (size_t)b * TLEN;
        #pragma unroll
        for (int j = 0; j < 8; j++) {
            int q = f*HOP + (kk + j) - 200;
            if (q < 0) q = -q;
            else if (q >= TLEN) q = 2*TLEN - 2 - q;
            v[j] = xb[q];
        }
    } else { // A_CONV3
        const int b = row / TSTEPS, t = row - b*TSTEPS;
        const int ksh = kk >> 7, i = kk & 127;
        const float* src = aux + ((size_t)(b*NFRAME + t + ksh)*NMEL + i);
        *(float4*)&v[0] = *(const float4*)(src);
        *(float4*)&v[4] = *(const float4*)(src + 4);
    }
}

template<int AMODE, bool BIAS>
__global__ __launch_bounds__(256)
void mgemm_k(const float* __restrict__ A,
             const unsigned short* __restrict__ BTh, const unsigned short* __restrict__ BTl,
             const float* __restrict__ bias, float* __restrict__ C,
             int M, int Ksteps, int lda, int kstride, int ldc,
             const float* __restrict__ aux, int rowbase)
{
    // double-buffered staging: one barrier per K-step, next-tile global loads
    // issued before compute so their latency hides behind MFMA
    __shared__ unsigned short Ash[2][64][LDK], Asl[2][64][LDK];
    __shared__ unsigned short Bsh[2][64][LDK], Bsl[2][64][LDK];

    const int tid = threadIdx.x;
    const int m0 = blockIdx.x * 64;
    const int n0 = blockIdx.y * 64;
    const int am = tid >> 2, k8 = (tid & 3) * 8;

    const int lane = tid & 63, w = tid >> 6;
    const int mrow = (w << 4) + (lane & 15);
    const int koff = (lane >> 4) * 8;

    f32x4 acc[4] = {{0,0,0,0},{0,0,0,0},{0,0,0,0},{0,0,0,0}};

    // ---- prologue: stage tile 0 ----
    {
        float v[8]; us8 hv, lv;
        load_a8<AMODE>(A, aux, rowbase, m0 + am, k8, lda, v);
        #pragma unroll
        for (int j = 0; j < 8; j++) { unsigned short h,l; bf_split_fast(v[j],h,l); hv[j]=h; lv[j]=l; }
        *(us8*)&Ash[0][am][k8] = hv;  *(us8*)&Asl[0][am][k8] = lv;
        const size_t o = (size_t)(n0 + am)*kstride + k8;
        *(us8*)&Bsh[0][am][k8] = *(const us8*)(BTh + o);
        *(us8*)&Bsl[0][am][k8] = *(const us8*)(BTl + o);
    }
    __syncthreads();

    for (int ks = 0; ks < Ksteps; ks++) {
        const int cur = ks & 1, nxt = cur ^ 1;
        const bool more = (ks + 1 < Ksteps);

        // issue next-tile global loads (consumed after compute)
        float nv[8]; us8 nbh, nbl;
        if (more) {
            const int kk = (ks + 1)*32 + k8;
            load_a8<AMODE>(A, aux, rowbase, m0 + am, kk, lda, nv);
            const size_t o = (size_t)(n0 + am)*kstride + kk;
            nbh = *(const us8*)(BTh + o);
            nbl = *(const us8*)(BTl + o);
        }

        // compute on current buffer
        bf16x8 ah = *(const bf16x8*)&Ash[cur][mrow][koff];
        bf16x8 al = *(const bf16x8*)&Asl[cur][mrow][koff];
        #pragma unroll
        for (int nt = 0; nt < 4; nt++) {
            const int nr = (nt << 4) + (lane & 15);
            bf16x8 bh = *(const bf16x8*)&Bsh[cur][nr][koff];
            bf16x8 bl = *(const bf16x8*)&Bsl[cur][nr][koff];
            acc[nt] = __builtin_amdgcn_mfma_f32_16x16x32_bf16(ah, bh, acc[nt], 0, 0, 0);
            acc[nt] = __builtin_amdgcn_mfma_f32_16x16x32_bf16(ah, bl, acc[nt], 0, 0, 0);
            acc[nt] = __builtin_amdgcn_mfma_f32_16x16x32_bf16(al, bh, acc[nt], 0, 0, 0);
        }

        if (more) {
            us8 hv, lv;
            #pragma unroll
            for (int j = 0; j < 8; j++) { unsigned short h,l; bf_split_fast(nv[j],h,l); hv[j]=h; lv[j]=l; }
            *(us8*)&Ash[nxt][am][k8] = hv;  *(us8*)&Asl[nxt][am][k8] = lv;
            *(us8*)&Bsh[nxt][am][k8] = nbh; *(us8*)&Bsl[nxt][am][k8] = nbl;
            __syncthreads();
        }
    }

    const int quad = lane >> 4;
    #pragma unroll
    for (int nt = 0; nt < 4; nt++) {
        const int col = n0 + (nt << 4) + (lane & 15);
        float b = 0.f;
        if constexpr (BIAS) b = bias[col];
        #pragma unroll
        for (int r = 0; r < 4; r++) {
            const int row = m0 + (w << 4) + quad*4 + r;
            C[(size_t)row*ldc + col] = acc[nt][r] + b;
        }
    }
    (void)M;
}

// ---------------- small fp32 GEMM (final 1024x35 only) ----------------
__global__ __launch_bounds__(256)
void gemm_small(const float* __restrict__ A, const float* __restrict__ Bm,
                const float* __restrict__ bias, float* __restrict__ C,
                int M, int N, int K, int lda, int ldb, int ldc)
{
    __shared__ float As[16][64+4];
    __shared__ float Bs[16][64];
    const int tid = threadIdx.x;
    const int tx = tid & 15, ty = tid >> 4;
    const int m0 = blockIdx.x * 64;
    float acc[4][4] = {{0,0,0,0},{0,0,0,0},{0,0,0,0},{0,0,0,0}};
    const int am = tid >> 2, ak = (tid & 3) * 4;
    const int bk = tid >> 4, bn = (tid & 15) * 4;
    for (int k0 = 0; k0 < K; k0 += 16) {
        float4 av = *(const float4*)(A + (size_t)(m0+am)*lda + k0 + ak);
        As[ak+0][am]=av.x; As[ak+1][am]=av.y; As[ak+2][am]=av.z; As[ak+3][am]=av.w;
        *(float4*)&Bs[bk][bn] = *(const float4*)(Bm + (size_t)(k0+bk)*ldb + bn);
        __syncthreads();
        #pragma unroll
        for (int k = 0; k < 16; k++) {
            float4 a = *(const float4*)&As[k][ty*4];
            float4 b = *(const float4*)&Bs[k][tx*4];
            #pragma unroll
            for (int i = 0; i < 4; i++) {
                float av_ = ((const float*)&a)[i];
                acc[i][0] = fmaf(av_, b.x, acc[i][0]);
                acc[i][1] = fmaf(av_, b.y, acc[i][1]);
                acc[i][2] = fmaf(av_, b.z, acc[i][2]);
                acc[i][3] = fmaf(av_, b.w, acc[i][3]);
            }
        }
        __syncthreads();
    }
    #pragma unroll
    for (int ir = 0; ir < 4; ir++) {
        const int row = m0 + ty*4 + ir;
        #pragma unroll
        for (int jc = 0; jc < 4; jc++) {
            const int col = tx*4 + jc;
            if (col < N) C[(size_t)row*ldc + col] = acc[ir][jc] + bias[col];
        }
    }
}

// ---------------- LSTM recurrence: MFMA, 16 batch rows / WG, 64 WGs ----------------
// The M=16 tile is now FULL (16 real rows). U-fragment refetch (if the
// compiler remats) costs 64 WGs x 131 KB/step = 1.05 MB/step/XCD -> 0.24 us
// L2 time per step — affordable regardless of allocator behavior (R5-R7
// lesson: it refuses to keep 64 regs of U live).
__device__ __forceinline__ float sigm_f(float x){ return 1.f/(1.f + __expf(-x)); }
__device__ __forceinline__ float tanh_f(float x){ float e = __expf(2.f*x); return 1.f - 2.f/(e + 1.f); }

#define LROWS 16
#define LTHREADS 512
#define HPAD 136
#define GPAD 20    // gs[c][row] leading dim: 20 words -> conflict-free b128 R/W

__global__ __launch_bounds__(LTHREADS)
void lstm_k(const float* __restrict__ X, const _Float16* __restrict__ Uf, float* __restrict__ H)
{
    __shared__ _Float16 hsA[16*HPAD];   // h, A-operand layout [row][k]
    __shared__ float gs[GATES*GPAD];    // gate exchange [c][row0..15 pad20]
    const int tid = threadIdx.x;
    const int b0 = blockIdx.x * LROWS;
    const int lane = tid & 63, w = tid >> 6;
    const int m16 = lane & 15, quad = lane >> 4;
    const int rq = (tid >> 7) * 4;      // nonlin: rows rq..rq+3
    const int j = tid & 127;            // nonlin: hidden index

    f32x4 bfr[4][4];
    #pragma unroll
    for (int ks = 0; ks < 4; ks++)
        #pragma unroll
        for (int nt = 0; nt < 4; nt++)
            bfr[ks][nt] = *(const f32x4*)(Uf + ((((w*4 + ks)*4 + nt)*64 + lane) << 3));

    for (int i = tid; i < 16*HPAD; i += LTHREADS) hsA[i] = (_Float16)0.f;
    float cst[4] = {0.f, 0.f, 0.f, 0.f};
    __syncthreads();

    // X prefetch (one step ahead): 4 cells x 4 gates
    float xv[4][4], xn[4][4];
    #pragma unroll
    for (int q = 0; q < 4; q++) {
        const float* p = X + ((size_t)(b0 + rq + q)*TSTEPS)*GATES + j;
        xv[q][0] = p[0]; xv[q][1] = p[128]; xv[q][2] = p[256]; xv[q][3] = p[384];
    }

    for (int t = 0; t < TSTEPS; t++) {
        if (t + 1 < TSTEPS) {
            #pragma unroll
            for (int q = 0; q < 4; q++) {
                const float* p = X + ((size_t)(b0 + rq + q)*TSTEPS + t + 1)*GATES + j;
                xn[q][0] = p[0]; xn[q][1] = p[128]; xn[q][2] = p[256]; xn[q][3] = p[384];
            }
        }

        f16x8 ah[4];
        #pragma unroll
        for (int ks = 0; ks < 4; ks++)
            ah[ks] = *(const f16x8*)&hsA[m16*HPAD + ks*32 + quad*8];

        f32x4 acc[4] = {{0,0,0,0},{0,0,0,0},{0,0,0,0},{0,0,0,0}};
        #pragma unroll
        for (int ks = 0; ks < 4; ks++)
            #pragma unroll
            for (int nt = 0; nt < 4; nt++)
                acc[nt] = __builtin_amdgcn_mfma_f32_16x16x32_f16(
                    ah[ks], __builtin_bit_cast(f16x8, bfr[ks][nt]), acc[nt], 0, 0, 0);

        // C rows quad*4..+3 (all real) -> one b128 per nt
        #pragma unroll
        for (int nt = 0; nt < 4; nt++) {
            const int c = w*64 + nt*16 + m16;
            *(f32x4*)&gs[c*GPAD + quad*4] = acc[nt];
        }
        __syncthreads();

        {
            const f32x4 Gi = *(const f32x4*)&gs[(      j)*GPAD + rq];
            const f32x4 Gf = *(const f32x4*)&gs[(128 + j)*GPAD + rq];
            const f32x4 Gg = *(const f32x4*)&gs[(256 + j)*GPAD + rq];
            const f32x4 Go = *(const f32x4*)&gs[(384 + j)*GPAD + rq];
            #pragma unroll
            for (int q = 0; q < 4; q++) {
                const float cn = sigm_f(Gf[q] + xv[q][1])*cst[q]
                               + sigm_f(Gi[q] + xv[q][0])*tanh_f(Gg[q] + xv[q][2]);
                cst[q] = cn;
                const float hn = sigm_f(Go[q] + xv[q][3])*tanh_f(cn);
                H[((size_t)(b0 + rq + q)*TSTEPS + t)*HID + j] = hn;
                hsA[(rq + q)*HPAD + j] = (_Float16)hn;
            }
        }
        __syncthreads();

        #pragma unroll
        for (int q = 0; q < 4; q++) {
            xv[q][0]=xn[q][0]; xv[q][1]=xn[q][1]; xv[q][2]=xn[q][2]; xv[q][3]=xn[q][3];
        }
    }
}

// ---------------- mean over time ----------------
__global__ void mean_k(const float* __restrict__ H, float* __restrict__ Mh){
    const int idx = blockIdx.x*256 + threadIdx.x;
    if (idx >= BATCH*HID) return;
    const int b = idx >> 7, j = idx & 127;
    const float* p = H + (size_t)b*TSTEPS*HID + j;
    float s = 0.f;
    for (int t = 0; t < TSTEPS; t++) s += p[(size_t)t*HID];
    Mh[idx] = s * (1.0f/(float)TSTEPS);
}

// ---------------- launcher ----------------
extern "C" void kernel_launch(void* const* d_in, const int* in_sizes, int n_in,
                              void* d_out, int out_size, void* d_ws, size_t ws_size,
                              hipStream_t stream)
{
    const float* x      = (const float*)d_in[0];
    const float* conv_w = (const float*)d_in[1];
    const float* conv_b = (const float*)d_in[2];
    const float* W1     = (const float*)d_in[3];
    const float* U1     = (const float*)d_in[4];
    const float* b1     = (const float*)d_in[5];
    const float* W2     = (const float*)d_in[6];
    const float* U2     = (const float*)d_in[7];
    const float* b2     = (const float*)d_in[8];
    const float* fc1_w  = (const float*)d_in[9];
    const float* fc1_b  = (const float*)d_in[10];
    const float* proj_w = (const float*)d_in[11];
    const float* proj_b = (const float*)d_in[12];
    float* out = (float*)d_out;

    // ---- workspace layout (~240 MiB < 256 MiB) ----
    char* ws = (char*)d_ws;
    size_t off = 0;
    unsigned short* Tth = (unsigned short*)(ws + off); off = al512(off + (size_t)NDFT*KDFT*2);
    unsigned short* Ttl = (unsigned short*)(ws + off); off = al512(off + (size_t)NDFT*KDFT*2);
    unsigned short* fbh = (unsigned short*)(ws + off); off = al512(off + (size_t)NMEL*KPOW*2);
    unsigned short* fbl = (unsigned short*)(ws + off); off = al512(off + (size_t)NMEL*KPOW*2);
    unsigned short* wch = (unsigned short*)(ws + off); off = al512(off + (size_t)NMEL*KCONV*2);
    unsigned short* wcl = (unsigned short*)(ws + off); off = al512(off + (size_t)NMEL*KCONV*2);
    unsigned short* w1h = (unsigned short*)(ws + off); off = al512(off + (size_t)GATES*HID*2);
    unsigned short* w1l = (unsigned short*)(ws + off); off = al512(off + (size_t)GATES*HID*2);
    unsigned short* w2h = (unsigned short*)(ws + off); off = al512(off + (size_t)GATES*HID*2);
    unsigned short* w2l = (unsigned short*)(ws + off); off = al512(off + (size_t)GATES*HID*2);
    float* Cw   = (float*)(ws + off); off = al512(off + (size_t)128*64*4);
    float* Cb   = (float*)(ws + off); off = al512(off + (size_t)64*4);
    float* Mh   = (float*)(ws + off); off = al512(off + (size_t)BATCH*HID*4);
    _Float16* Uf1 = (_Float16*)(ws + off); off = al512(off + (size_t)65536*2);
    _Float16* Uf2 = (_Float16*)(ws + off); off = al512(off + (size_t)65536*2);
    float* MEL  = (float*)(ws + off); off = al512(off + (size_t)BATCH*NFRAME*NMEL*4);   // 42.5 MB
    float* CONV = (float*)(ws + off); off = al512(off + (size_t)BATCH*TSTEPS*NMEL*4);   // 41.4 MB
    float* X    = (float*)(ws + off); off = al512(off + (size_t)BATCH*TSTEPS*GATES*4);  // 165.7 MB
    float* DFT = X;     // full-size DFT scratch (148.6 MB <= 165.7) dead before X written
    float* H1  = MEL;   // MEL dead after CONV computed
    float* H2  = CONV;  // CONV dead after X1 computed
    (void)ws_size; (void)out_size; (void)n_in; (void)in_sizes;

    // setup tables
    setup_dft_t<<<(NDFT*KDFT + 255)/256, 256, 0, stream>>>(Tth, Ttl);
    setup_fb_t <<<(NMEL*KPOW + 255)/256, 256, 0, stream>>>(fbh, fbl);
    setup_wc_t <<<(NMEL*KCONV + 255)/256, 256, 0, stream>>>(wch, wcl, conv_w);
    setup_w_t  <<<(GATES*HID + 255)/256, 256, 0, stream>>>(w1h, w1l, W1);
    setup_w_t  <<<(GATES*HID + 255)/256, 256, 0, stream>>>(w2h, w2l, W2);
    setup_comb <<<(128*64 + 64 + 255)/256, 256, 0, stream>>>(Cw, Cb, fc1_w, fc1_b, proj_w, proj_b);
    setup_uf   <<<65536/256, 256, 0, stream>>>(Uf1, U1);
    setup_uf   <<<65536/256, 256, 0, stream>>>(Uf2, U2);

    // mel spectrogram (single pass): frames @ DFT -> power @ fb
    mgemm_k<A_FRAMES,false><<<dim3(MROWS/64, NDFT/64), 256, 0, stream>>>(
        nullptr, Tth, Ttl, nullptr, DFT, MROWS, KDFT/32, 0, KDFT, NDFT, x, 0);
    mgemm_k<A_POWER,false><<<dim3(MROWS/64, NMEL/64), 256, 0, stream>>>(
        DFT, fbh, fbl, nullptr, MEL, MROWS, KPOW/32, NDFT, KPOW, NMEL, nullptr, 0);

    // conv1d (k=3, valid) as im2col GEMM, bias fused
    mgemm_k<A_CONV3,true><<<dim3(BATCH*TSTEPS/64, NMEL/64), 256, 0, stream>>>(
        nullptr, wch, wcl, conv_b, CONV, BATCH*TSTEPS, KCONV/32, 0, KCONV, NMEL, MEL, 0);

    // layer 1: X1 = CONV @ W1 + b1 ; recurrence
    mgemm_k<A_NORMAL,true><<<dim3(BATCH*TSTEPS/64, GATES/64), 256, 0, stream>>>(
        CONV, w1h, w1l, b1, X, BATCH*TSTEPS, HID/32, NMEL, HID, GATES, nullptr, 0);
    lstm_k<<<BATCH/LROWS, LTHREADS, 0, stream>>>(X, Uf1, H1);

    // layer 2
    mgemm_k<A_NORMAL,true><<<dim3(BATCH*TSTEPS/64, GATES/64), 256, 0, stream>>>(
        H1, w2h, w2l, b2, X, BATCH*TSTEPS, HID/32, HID, HID, GATES, nullptr, 0);
    lstm_k<<<BATCH/LROWS, LTHREADS, 0, stream>>>(X, Uf2, H2);

    // mean over time, then folded fc1+proj
    mean_k<<<(BATCH*HID + 255)/256, 256, 0, stream>>>(H2, Mh);
    gemm_small<<<BATCH/64, 256, 0, stream>>>(Mh, Cw, Cb, out, BATCH, 35, HID, HID, 64, 35);
}